// Round 11
// baseline (892.070 us; speedup 1.0000x reference)
//
#include <hip/hip_runtime.h>
#include <cstdint>
#include <cstddef>

static constexpr int NN = 24000;   // nodes
static constexpr int NE = 96000;   // edges
static constexpr int NB = 1200;    // graphs
static constexpr int NPG = 20;     // nodes per graph
static constexpr int MPAD = 24064; // NN padded to 128

typedef __attribute__((ext_vector_type(8))) short bfv8;
typedef __attribute__((ext_vector_type(4))) float fv4;

// ---- ordered-uint mapping for float max (memset-free; -inf maps consistently) ----
__device__ __forceinline__ unsigned f2ord(float f){
  unsigned u = __float_as_uint(f);
  return (u & 0x80000000u) ? ~u : (u | 0x80000000u);
}
__device__ __forceinline__ float ord2f(unsigned u){
  return (u & 0x80000000u) ? __uint_as_float(u & 0x7FFFFFFFu)
                           : __uint_as_float(~u);
}
__device__ __forceinline__ unsigned short f2bf(float f){
  unsigned u = __float_as_uint(f);
  u += 0x7FFFu + ((u >> 16) & 1u);   // RNE
  return (unsigned short)(u >> 16);
}
__device__ __forceinline__ float bf2f(unsigned short s){
  return __uint_as_float(((unsigned)s) << 16);
}

// ---------------- CSR build ----------------
__global__ __launch_bounds__(256) void count_kernel(const int* __restrict__ dst,
                                                    unsigned* __restrict__ deg)
{
  int e = blockIdx.x*256 + threadIdx.x;
  if (e < NE) atomicAdd(&deg[dst[e]], 1u);
}

__global__ __launch_bounds__(1024) void scan_kernel(const unsigned* __restrict__ deg,
                                                    unsigned* __restrict__ rowstart)
{
  __shared__ unsigned s[1024];
  __shared__ unsigned carry_s;
  int tid = threadIdx.x;
  if (tid == 0) carry_s = 0;
  __syncthreads();
  for (int base = 0; base < NN; base += 1024){
    unsigned v = (base + tid < NN) ? deg[base + tid] : 0u;
    s[tid] = v;
    __syncthreads();
#pragma unroll
    for (int off = 1; off < 1024; off <<= 1){
      unsigned t = (tid >= off) ? s[tid - off] : 0u;
      __syncthreads();
      s[tid] += t;
      __syncthreads();
    }
    unsigned carry = carry_s;
    if (base + tid < NN) rowstart[base + tid] = carry + s[tid] - v;
    __syncthreads();
    if (tid == 0) carry_s = carry + s[1023];
    __syncthreads();
  }
  if (tid == 0) rowstart[NN] = carry_s;
}

__global__ __launch_bounds__(256) void scatter_kernel(const int* __restrict__ dst,
                                                      const unsigned* __restrict__ rowstart,
                                                      unsigned* __restrict__ cur,
                                                      int* __restrict__ eidx)
{
  int e = blockIdx.x*256 + threadIdx.x;
  if (e >= NE) return;
  int d = dst[e];
  unsigned p = rowstart[d] + atomicAdd(&cur[d], 1u);
  eidx[p] = e;
}

// ---------------- layer-1 node projections (K=9), two outputs per pass ----------------
template<bool BA, bool BB>
__global__ __launch_bounds__(256) void node_gemm_l1_pair(
    const float* __restrict__ x,
    const float* __restrict__ Wa, const float* __restrict__ ba,
    const float* __restrict__ Wb, const float* __restrict__ bb,
    void* __restrict__ outa, void* __restrict__ outb)
{
  int t = blockIdx.x*256 + threadIdx.x;
  if (t >= NN*512) return;
  int n = t >> 9, j = t & 511;
  float xr[9];
#pragma unroll
  for (int i=0;i<9;i++) xr[i] = x[n*9+i];
  float aa=ba[j], ab=bb[j];
#pragma unroll
  for (int i=0;i<9;i++){
    float xi = xr[i];
    aa += xi*Wa[i*512+j];
    ab += xi*Wb[i*512+j];
  }
  if (BA) ((unsigned short*)outa)[t] = f2bf(aa); else ((float*)outa)[t] = aa;
  if (BB) ((unsigned short*)outb)[t] = f2bf(ab); else ((float*)outb)[t] = ab;
}

// ---------------- t[n][h][c] = sum_{f in head h} q[n,f] * We[c,f]  (HC=512) ----------------
__global__ __launch_bounds__(256) void tproj512_kernel(
    const unsigned short* __restrict__ q, const float* __restrict__ We,
    float* __restrict__ t)
{
  int wave = (blockIdx.x*256 + threadIdx.x) >> 6;
  int lane = threadIdx.x & 63;
  if (wave >= NN) return;
  int off = lane*8;
  bfv8 qv = *reinterpret_cast<const bfv8*>(q + (size_t)wave*512 + off);
  float p0=0.f,p1=0.f,p2=0.f,p3=0.f;
#pragma unroll
  for (int j=0;j<8;j++){
    float qf = bf2f((unsigned short)qv[j]);
    int f = off + j;
    p0 += qf*We[f]; p1 += qf*We[512+f]; p2 += qf*We[1024+f]; p3 += qf*We[1536+f];
  }
#pragma unroll
  for (int o=8;o>=1;o>>=1){
    p0 += __shfl_xor(p0,o); p1 += __shfl_xor(p1,o);
    p2 += __shfl_xor(p2,o); p3 += __shfl_xor(p3,o);
  }
  if ((lane & 15) == 0){
    int h = lane >> 4;
    *reinterpret_cast<float4*>(t + (size_t)wave*16 + h*4) = make_float4(p0,p1,p2,p3);
  }
}

// ---------------- same for HC=1024 ----------------
__global__ __launch_bounds__(256) void tproj1024_kernel(
    const unsigned short* __restrict__ q, const float* __restrict__ We,
    float* __restrict__ t)
{
  int wave = (blockIdx.x*256 + threadIdx.x) >> 6;
  int lane = threadIdx.x & 63;
  if (wave >= NN) return;
  float p0=0.f,p1=0.f,p2=0.f,p3=0.f;
#pragma unroll
  for (int half=0; half<2; ++half){
    int off = lane*16 + half*8;
    bfv8 qv = *reinterpret_cast<const bfv8*>(q + (size_t)wave*1024 + off);
#pragma unroll
    for (int j=0;j<8;j++){
      float qf = bf2f((unsigned short)qv[j]);
      int f = off + j;
      p0 += qf*We[f]; p1 += qf*We[1024+f]; p2 += qf*We[2048+f]; p3 += qf*We[3072+f];
    }
  }
#pragma unroll
  for (int o=8;o>=1;o>>=1){
    p0 += __shfl_xor(p0,o); p1 += __shfl_xor(p1,o);
    p2 += __shfl_xor(p2,o); p3 += __shfl_xor(p3,o);
  }
  if ((lane & 15) == 0){
    int h = lane >> 4;
    *reinterpret_cast<float4*>(t + (size_t)wave*16 + h*4) = make_float4(p0,p1,p2,p3);
  }
}

// ---------------- per-graph L1 alpha (HC=512): LDS-staged q/k, direct amax ----------------
__global__ __launch_bounds__(256) void alpha_g512(
    const unsigned short* __restrict__ q, const unsigned short* __restrict__ k,
    const float* __restrict__ ea, const float* __restrict__ t,
    const int* __restrict__ src,
    const unsigned* __restrict__ rowstart, const int* __restrict__ eidx,
    float* __restrict__ alpha, unsigned* __restrict__ amax)
{
  __shared__ unsigned short qs[NPG*512];
  __shared__ unsigned short ks[NPG*512];
  int g = blockIdx.x, base = g*NPG;
  int tid = threadIdx.x;
  for (int c = tid; c < NPG*64; c += 256){
    int i = c >> 6, col = (c & 63)*8;
    *reinterpret_cast<uint4*>(qs + i*512 + col) =
        *reinterpret_cast<const uint4*>(q + (size_t)(base+i)*512 + col);
    *reinterpret_cast<uint4*>(ks + i*512 + col) =
        *reinterpret_cast<const uint4*>(k + (size_t)(base+i)*512 + col);
  }
  __syncthreads();
  int w = tid >> 6, lane = tid & 63;
  const float scale = 0.088388347648318447f;   // 1/sqrt(128)
  bool hl = (lane & 15) == 0;
  int h = lane >> 4;
  for (int dl = w; dl < NPG; dl += 4){
    int d = base + dl;
    unsigned p0 = rowstart[d], p1 = rowstart[d+1];
    float mx = -__builtin_inff();
    float4 tv = make_float4(0,0,0,0);
    if (hl) tv = *reinterpret_cast<const float4*>(t + (size_t)d*16 + h*4);
    bfv8 qv = *reinterpret_cast<const bfv8*>(qs + dl*512 + lane*8);
    for (unsigned pp = p0; pp < p1; ++pp){
      int e = eidx[pp];
      int ls = src[e] - base;
      bfv8 kv = *reinterpret_cast<const bfv8*>(ks + ls*512 + lane*8);
      float part = 0.f;
#pragma unroll
      for (int j=0;j<8;j++)
        part += bf2f((unsigned short)qv[j]) * bf2f((unsigned short)kv[j]);
#pragma unroll
      for (int o=8;o>=1;o>>=1) part += __shfl_xor(part,o);
      if (hl){
        float4 eav = *reinterpret_cast<const float4*>(ea + (size_t)e*4);
        float a = (part + eav.x*tv.x + eav.y*tv.y + eav.z*tv.z + eav.w*tv.w)*scale;
        alpha[e*4+h] = a;
        mx = fmaxf(mx, a);
      }
    }
    if (hl) amax[d*4+h] = f2ord(mx);
  }
}

// ---------------- per-graph L2 alpha (HC=1024, head-half split) ----------------
__global__ __launch_bounds__(256) void alpha_g1024(
    const unsigned short* __restrict__ q, const unsigned short* __restrict__ k,
    const float* __restrict__ ea, const float* __restrict__ t,
    const int* __restrict__ src,
    const unsigned* __restrict__ rowstart, const int* __restrict__ eidx,
    float* __restrict__ alpha, unsigned* __restrict__ amax)
{
  __shared__ unsigned short qs[NPG*512];
  __shared__ unsigned short ks[NPG*512];
  int g = blockIdx.x, base = g*NPG;
  int p = blockIdx.y;
  int tid = threadIdx.x;
  for (int c = tid; c < NPG*64; c += 256){
    int i = c >> 6, col = (c & 63)*8;
    *reinterpret_cast<uint4*>(qs + i*512 + col) =
        *reinterpret_cast<const uint4*>(q + (size_t)(base+i)*1024 + p*512 + col);
    *reinterpret_cast<uint4*>(ks + i*512 + col) =
        *reinterpret_cast<const uint4*>(k + (size_t)(base+i)*1024 + p*512 + col);
  }
  __syncthreads();
  int w = tid >> 6, lane = tid & 63;
  const float scale = 1.0f/16.0f;   // 1/sqrt(256)
  bool hl = (lane & 31) == 0;
  int h = p*2 + (lane >> 5);
  for (int dl = w; dl < NPG; dl += 4){
    int d = base + dl;
    unsigned p0 = rowstart[d], p1 = rowstart[d+1];
    float mx = -__builtin_inff();
    float4 tv = make_float4(0,0,0,0);
    if (hl) tv = *reinterpret_cast<const float4*>(t + (size_t)d*16 + h*4);
    bfv8 qv = *reinterpret_cast<const bfv8*>(qs + dl*512 + lane*8);
    for (unsigned pp = p0; pp < p1; ++pp){
      int e = eidx[pp];
      int ls = src[e] - base;
      bfv8 kv = *reinterpret_cast<const bfv8*>(ks + ls*512 + lane*8);
      float part = 0.f;
#pragma unroll
      for (int j=0;j<8;j++)
        part += bf2f((unsigned short)qv[j]) * bf2f((unsigned short)kv[j]);
#pragma unroll
      for (int o=16;o>=1;o>>=1) part += __shfl_xor(part,o);
      if (hl){
        float4 eav = *reinterpret_cast<const float4*>(ea + (size_t)e*4);
        float a = (part + eav.x*tv.x + eav.y*tv.y + eav.z*tv.z + eav.w*tv.w)*scale;
        alpha[e*4+h] = a;
        mx = fmaxf(mx, a);
      }
    }
    if (hl) amax[d*4+h] = f2ord(mx);
  }
}

// ---------------- exp + denominator ----------------
__global__ __launch_bounds__(256) void ex_kernel(
    float* __restrict__ alpha, const unsigned* __restrict__ amax,
    const int* __restrict__ dst, float* __restrict__ den)
{
  int t = blockIdx.x*256 + threadIdx.x;
  if (t >= NE*4) return;
  int e = t>>2, h = t&3;
  int d = dst[e];
  float m = ord2f(amax[d*4+h]);
  float v = __expf(alpha[t]-m);
  alpha[t] = v;
  unsafeAtomicAdd(&den[d*4+h], v);
}

// ---------------- CSR gather L1: bf16 v, fp32 s1 init, bf16 relu'd output ----------------
__global__ __launch_bounds__(256) void gather512_kernel(
    const unsigned short* __restrict__ v, const float* __restrict__ ea,
    const float* __restrict__ We,
    const int* __restrict__ src,
    const unsigned* __restrict__ rowstart, const int* __restrict__ eidx,
    const float* __restrict__ exw, const float* __restrict__ den,
    const float* __restrict__ accin, unsigned short* __restrict__ hb)
{
  int n = blockIdx.x;
  int tid = threadIdx.x;
  int h = tid >> 6;
  int f2 = tid*2;
  unsigned p0 = rowstart[n], p1 = rowstart[n+1];
  float2 W0 = *reinterpret_cast<const float2*>(We + 0*512 + f2);
  float2 W1 = *reinterpret_cast<const float2*>(We + 1*512 + f2);
  float2 W2 = *reinterpret_cast<const float2*>(We + 2*512 + f2);
  float2 W3 = *reinterpret_cast<const float2*>(We + 3*512 + f2);
  float rdn = 1.0f / (den[n*4+h] + 1e-16f);
  float2 s = *reinterpret_cast<const float2*>(accin + (size_t)n*512 + f2);
  for (unsigned p = p0; p < p1; ++p){
    int e  = eidx[p];
    float w = exw[e*4+h] * rdn;
    float4 eav = *reinterpret_cast<const float4*>(ea + (size_t)e*4);
    ushort2 vv = *reinterpret_cast<const ushort2*>(v + (size_t)src[e]*512 + f2);
    float efx = eav.x*W0.x + eav.y*W1.x + eav.z*W2.x + eav.w*W3.x;
    float efy = eav.x*W0.y + eav.y*W1.y + eav.z*W2.y + eav.w*W3.y;
    s.x += w*(bf2f(vv.x) + efx);
    s.y += w*(bf2f(vv.y) + efy);
  }
  ushort2 o;
  o.x = f2bf(fmaxf(s.x, 0.0f));
  o.y = f2bf(fmaxf(s.y, 0.0f));
  *reinterpret_cast<ushort2*>(hb + (size_t)n*512 + f2) = o;
}

// ---------------- CSR gather L2: bf16 v, fp32 acc in-place ----------------
__global__ __launch_bounds__(256) void gather1024_kernel(
    const unsigned short* __restrict__ v, const float* __restrict__ ea,
    const float* __restrict__ We,
    const int* __restrict__ src,
    const unsigned* __restrict__ rowstart, const int* __restrict__ eidx,
    const float* __restrict__ exw, const float* __restrict__ den,
    float* __restrict__ acc)
{
  int n = blockIdx.x;
  int tid = threadIdx.x;
  int h = tid >> 6;
  int f4 = tid*4;
  unsigned p0 = rowstart[n], p1 = rowstart[n+1];
  float4 W0 = *reinterpret_cast<const float4*>(We + 0*1024 + f4);
  float4 W1 = *reinterpret_cast<const float4*>(We + 1*1024 + f4);
  float4 W2 = *reinterpret_cast<const float4*>(We + 2*1024 + f4);
  float4 W3 = *reinterpret_cast<const float4*>(We + 3*1024 + f4);
  float rdn = 1.0f / (den[n*4+h] + 1e-16f);
  float4 s = *reinterpret_cast<float4*>(acc + (size_t)n*1024 + f4);
  for (unsigned p = p0; p < p1; ++p){
    int e  = eidx[p];
    float w = exw[e*4+h] * rdn;
    float4 eav = *reinterpret_cast<const float4*>(ea + (size_t)e*4);
    ushort4 vv = *reinterpret_cast<const ushort4*>(v + (size_t)src[e]*1024 + f4);
    s.x += w*(bf2f(vv.x) + eav.x*W0.x + eav.y*W1.x + eav.z*W2.x + eav.w*W3.x);
    s.y += w*(bf2f(vv.y) + eav.x*W0.y + eav.y*W1.y + eav.z*W2.y + eav.w*W3.y);
    s.z += w*(bf2f(vv.z) + eav.x*W0.z + eav.y*W1.z + eav.z*W2.z + eav.w*W3.z);
    s.w += w*(bf2f(vv.w) + eav.x*W0.w + eav.y*W1.w + eav.z*W2.w + eav.w*W3.w);
  }
  *reinterpret_cast<float4*>(acc + (size_t)n*1024 + f4) = s;
}

// ---------------- W[512,1024] -> Wt[1024,512] bf16 ----------------
__global__ __launch_bounds__(256) void cvt_wt_kernel(const float* __restrict__ W,
                                                     unsigned short* __restrict__ Wt)
{
  int t = blockIdx.x*256 + threadIdx.x;
  if (t >= 1024*512) return;
  int n = t >> 9, k = t & 511;
  Wt[t] = f2bf(W[k*1024 + n]);
}

// ---------------- bf16 MFMA GEMM: out[M,1024] = A[MPAD,512]@Wt^T + bias ----------------
template<bool BOUT>
__global__ __launch_bounds__(256) void gemm_bf16_mfma(
    const unsigned short* __restrict__ A,
    const unsigned short* __restrict__ B,   // Wt
    const float* __restrict__ bias,
    void* __restrict__ Cout, int M)
{
  constexpr int K = 512, N = 1024;
  __shared__ unsigned short As[128*32];
  __shared__ unsigned short Bs[128*32];
  int tid  = threadIdx.x;
  int wid  = tid >> 6, lane = tid & 63;
  int wr   = wid >> 1, wc = wid & 1;
  int bm   = blockIdx.y * 128, bn = blockIdx.x * 128;
  int l15  = lane & 15, kg = lane >> 4;

  int r0 = (wid*2+0)*16 + (lane>>2);
  int r1 = (wid*2+1)*16 + (lane>>2);
  int s0 = lane & 3;
  int kc0 = s0 ^ ((r0>>1)&3);
  int kc1 = s0 ^ ((r1>>1)&3);
  unsigned short* ldsA0 = As + (wid*2+0)*512;
  unsigned short* ldsA1 = As + (wid*2+1)*512;
  unsigned short* ldsB0 = Bs + (wid*2+0)*512;
  unsigned short* ldsB1 = Bs + (wid*2+1)*512;

  fv4 acc[4][4];
#pragma unroll
  for (int m=0;m<4;m++)
#pragma unroll
    for (int n=0;n<4;n++) acc[m][n] = (fv4){0.f,0.f,0.f,0.f};

  for (int k0 = 0; k0 < K; k0 += 32){
    __syncthreads();
    __builtin_amdgcn_global_load_lds(
        (const __attribute__((address_space(1))) void*)(A + (size_t)(bm+r0)*K + k0 + kc0*8),
        (__attribute__((address_space(3))) void*)ldsA0, 16, 0, 0);
    __builtin_amdgcn_global_load_lds(
        (const __attribute__((address_space(1))) void*)(A + (size_t)(bm+r1)*K + k0 + kc1*8),
        (__attribute__((address_space(3))) void*)ldsA1, 16, 0, 0);
    __builtin_amdgcn_global_load_lds(
        (const __attribute__((address_space(1))) void*)(B + (size_t)(bn+r0)*K + k0 + kc0*8),
        (__attribute__((address_space(3))) void*)ldsB0, 16, 0, 0);
    __builtin_amdgcn_global_load_lds(
        (const __attribute__((address_space(1))) void*)(B + (size_t)(bn+r1)*K + k0 + kc1*8),
        (__attribute__((address_space(3))) void*)ldsB1, 16, 0, 0);
    __syncthreads();
    bfv8 af[4], bfr[4];
#pragma unroll
    for (int m=0;m<4;m++){
      int r  = wr*64 + m*16 + l15;
      int sl = kg ^ ((r>>1)&3);
      af[m] = *reinterpret_cast<const bfv8*>(reinterpret_cast<char*>(As) + r*64 + sl*16);
    }
#pragma unroll
    for (int n=0;n<4;n++){
      int r  = wc*64 + n*16 + l15;
      int sl = kg ^ ((r>>1)&3);
      bfr[n] = *reinterpret_cast<const bfv8*>(reinterpret_cast<char*>(Bs) + r*64 + sl*16);
    }
#pragma unroll
    for (int m=0;m<4;m++)
#pragma unroll
      for (int n=0;n<4;n++)
        acc[m][n] = __builtin_amdgcn_mfma_f32_16x16x32_bf16(af[m], bfr[n], acc[m][n], 0, 0, 0);
  }
#pragma unroll
  for (int m=0;m<4;m++){
#pragma unroll
    for (int n=0;n<4;n++){
      int col = bn + wc*64 + n*16 + l15;
      float bcol = bias[col];
#pragma unroll
      for (int r=0;r<4;r++){
        int row = bm + wr*64 + m*16 + (lane>>4)*4 + r;
        if (row < M){
          float val = acc[m][n][r] + bcol;
          if (BOUT) ((unsigned short*)Cout)[(size_t)row*N + col] = f2bf(val);
          else      ((float*)Cout)[(size_t)row*N + col] = val;
        }
      }
    }
  }
}

// ---------------- split-K fp32 GEMM to partial slabs (no atomics) ----------------
__global__ __launch_bounds__(256) void sgemm_partial(
    const float* __restrict__ A, const float* __restrict__ W,
    float* __restrict__ P, int M, int N, int K, int kchunk, int zoff)
{
  __shared__ float As[32][68];
  __shared__ __align__(16) float Bs[32][64];
  int tid = threadIdx.x;
  int bm = blockIdx.y*64, bn = blockIdx.x*64;
  int kbeg = blockIdx.z*kchunk;
  int kend = min(kbeg + kchunk, K);
  float* Pz = P + (size_t)(zoff + blockIdx.z)*M*N;
  int ty = tid >> 4, tx = tid & 15;
  float acc[4][4] = {};
  for (int k0 = kbeg; k0 < kend; k0 += 32){
#pragma unroll
    for (int i=0;i<2;i++){
      int lin = tid + i*256;
      int r = lin >> 3;
      int kq = (lin & 7) * 4;
      float4 av = make_float4(0.f,0.f,0.f,0.f);
      int row = bm + r;
      if (row < M) av = *reinterpret_cast<const float4*>(A + (size_t)row*K + k0 + kq);
      As[kq+0][r]=av.x; As[kq+1][r]=av.y; As[kq+2][r]=av.z; As[kq+3][r]=av.w;
    }
#pragma unroll
    for (int i=0;i<2;i++){
      int lin = tid + i*256;
      int kr = lin >> 4;
      int c4 = (lin & 15) * 4;
      float4 wv = *reinterpret_cast<const float4*>(W + (size_t)(k0+kr)*N + bn + c4);
      *reinterpret_cast<float4*>(&Bs[kr][c4]) = wv;
    }
    __syncthreads();
#pragma unroll
    for (int kk=0;kk<32;kk++){
      float a[4], b[4];
#pragma unroll
      for (int i=0;i<4;i++) a[i] = As[kk][ty*4+i];
#pragma unroll
      for (int j=0;j<4;j++) b[j] = Bs[kk][tx*4+j];
#pragma unroll
      for (int i=0;i<4;i++)
#pragma unroll
        for (int j=0;j<4;j++) acc[i][j] += a[i]*b[j];
    }
    __syncthreads();
  }
#pragma unroll
  for (int i=0;i<4;i++){
    int row = bm + ty*4 + i;
    if (row >= M) break;
#pragma unroll
    for (int j=0;j<4;j++)
      Pz[(size_t)row*N + bn + tx*4 + j] = acc[i][j];
  }
}

// ---------------- O[t] = bias[t&nmask] + sum_z P[z][t] ----------------
__global__ __launch_bounds__(256) void reduce_add_kernel(
    const float* __restrict__ P, const float* __restrict__ bias,
    float* __restrict__ O, int total, int nz, int nmask)
{
  int t = blockIdx.x*256 + threadIdx.x;
  if (t >= total) return;
  float s = bias[t & nmask];
  for (int z = 0; z < nz; ++z) s += P[(size_t)z*total + t];
  O[t] = s;
}

// ---------------- mean pool (float4) ----------------
__global__ __launch_bounds__(256) void pool_kernel(const float* __restrict__ h2,
                                                   float* __restrict__ g)
{
  int t = blockIdx.x*256 + threadIdx.x;
  if (t >= NB*256) return;
  int b = t >> 8, f4 = (t & 255) * 4;
  float4 s = make_float4(0.f,0.f,0.f,0.f);
#pragma unroll
  for (int i=0;i<NPG;i++){
    float4 v = *reinterpret_cast<const float4*>(h2 + (size_t)(b*NPG+i)*1024 + f4);
    s.x += v.x; s.y += v.y; s.z += v.z; s.w += v.w;
  }
  s.x *= (1.0f/NPG); s.y *= (1.0f/NPG); s.z *= (1.0f/NPG); s.w *= (1.0f/NPG);
  *reinterpret_cast<float4*>(g + (size_t)b*1024 + f4) = s;
}

extern "C" void kernel_launch(void* const* d_in, const int* in_sizes, int n_in,
                              void* d_out, int out_size, void* d_ws, size_t ws_size,
                              hipStream_t stream)
{
  const float* x    = (const float*)d_in[0];
  const int*   ei   = (const int*)d_in[1];
  const float* ea   = (const float*)d_in[2];
  const float* fpb  = (const float*)d_in[4];
  const float* Wq1  = (const float*)d_in[5];  const float* bq1 = (const float*)d_in[6];
  const float* Wk1  = (const float*)d_in[7];  const float* bk1 = (const float*)d_in[8];
  const float* Wv1  = (const float*)d_in[9];  const float* bv1 = (const float*)d_in[10];
  const float* We1  = (const float*)d_in[11];
  const float* Ws1  = (const float*)d_in[12]; const float* bs1 = (const float*)d_in[13];
  const float* Wq2  = (const float*)d_in[14]; const float* bq2 = (const float*)d_in[15];
  const float* Wk2  = (const float*)d_in[16]; const float* bk2 = (const float*)d_in[17];
  const float* Wv2  = (const float*)d_in[18]; const float* bv2 = (const float*)d_in[19];
  const float* We2  = (const float*)d_in[20];
  const float* Ws2  = (const float*)d_in[21]; const float* bs2 = (const float*)d_in[22];
  const float* Wfp  = (const float*)d_in[23]; const float* bfp = (const float*)d_in[24];
  const float* Wfin = (const float*)d_in[25]; const float* bfin= (const float*)d_in[26];
  const int* src = ei;
  const int* dst = ei + NE;
  float* out = (float*)d_out;

  // ---- workspace layout (~257 MB peak, time-disjoint aliasing) ----
  const size_t F512  = (size_t)NN*512;
  const size_t F1024 = (size_t)NN*1024;
  float* base = (float*)d_ws;
  float* C_a = base;                    // q1b/v1b; q2b/v2b (bf16); hb at +F1024 ushorts; P1/P2
  float* C_b = base + F1024;            // k2b (bf16); s2/acc2 fp32
  float* H   = base + 2*F1024;          // k1b (bf16); s1 fp32; later Wt (bf16)
  unsigned short* q1b = (unsigned short*)C_a;        // [NN,512]
  unsigned short* v1b = (unsigned short*)C_a;        // [NN,512] (q1b dead)
  unsigned short* k1b = (unsigned short*)H;          // [NN,512]
  float*          s1  = H;                           // [NN,512] fp32 (k1b dead)
  unsigned short* hb  = (unsigned short*)C_a + F1024;   // [MPAD,512] bf16
  unsigned short* q2b = (unsigned short*)C_a;        // [NN,1024] bf16
  unsigned short* k2b = (unsigned short*)C_b;        // [NN,1024] bf16
  unsigned short* v2b = (unsigned short*)C_a;        // [NN,1024] bf16 (q2b dead)
  float*          s2  = C_b;                         // [NN,1024] fp32 (k2b dead)
  unsigned short* WtQ = (unsigned short*)H;          // 4 x [1024,512] bf16 (s1 dead)
  unsigned short* WtK = WtQ + (size_t)1024*512;
  unsigned short* WtV = WtK + (size_t)1024*512;
  unsigned short* WtS = WtV + (size_t)1024*512;
  float* P1 = C_a;                            // 5 x [NB*1024]
  float* P2 = C_a + 5*(size_t)NB*1024;        // 8 x [NB*256]

  float* tail = base + 2*F1024 + F512;
  float*    alphab   = tail;                                  // NE*4 (scores -> exp)
  unsigned* amax     = (unsigned*)(alphab + (size_t)NE*4);    // NN*4
  float*    den      = (float*)(amax + (size_t)NN*4);         // NN*4
  unsigned* deg      = (unsigned*)(den + (size_t)NN*4);       // NN
  unsigned* cur      = deg + NN;                              // NN
  unsigned* rowstart = cur + NN;                              // NN+1
  int*      eidx     = (int*)(rowstart + NN + 1);             // NE
  float*    g        = (float*)(eidx + NE);                   // NB*1024
  float*    fp       = g + (size_t)NB*1024;                   // NB*256
  float*    tproj    = fp + (size_t)NB*256;                   // NN*16 (t1 then t2)

  // ================= CSR build =================
  hipMemsetAsync(deg, 0, sizeof(unsigned)*NN, stream);
  hipMemsetAsync(cur, 0, sizeof(unsigned)*NN, stream);
  count_kernel<<<(NE+255)/256, 256, 0, stream>>>(dst, deg);
  scan_kernel<<<1, 1024, 0, stream>>>(deg, rowstart);
  scatter_kernel<<<(NE+255)/256, 256, 0, stream>>>(dst, rowstart, cur, eidx);

  // ================= Layer 1 =================
  hipMemsetAsync(den, 0, sizeof(float)*(size_t)NN*4, stream);

  node_gemm_l1_pair<true,true><<<(NN*512+255)/256, 256, 0, stream>>>(
      x, Wq1,bq1, Wk1,bk1, q1b, k1b);
  tproj512_kernel<<<(NN*64+255)/256, 256, 0, stream>>>(q1b, We1, tproj);
  alpha_g512<<<NB, 256, 0, stream>>>(q1b, k1b, ea, tproj, src, rowstart, eidx,
                                     alphab, amax);
  ex_kernel<<<(NE*4+255)/256, 256, 0, stream>>>(alphab, amax, dst, den);
  node_gemm_l1_pair<true,false><<<(NN*512+255)/256, 256, 0, stream>>>(
      x, Wv1,bv1, Ws1,bs1, v1b, s1);
  gather512_kernel<<<NN, 256, 0, stream>>>(v1b, ea, We1, src, rowstart, eidx,
                                           alphab, den, s1, hb);
  hipMemsetAsync(hb + F512, 0, (size_t)(MPAD-NN)*512*sizeof(unsigned short), stream);

  // ================= weights to bf16 (H free: s1 dead) =================
  cvt_wt_kernel<<<(1024*512+255)/256, 256, 0, stream>>>(Wq2, WtQ);
  cvt_wt_kernel<<<(1024*512+255)/256, 256, 0, stream>>>(Wk2, WtK);
  cvt_wt_kernel<<<(1024*512+255)/256, 256, 0, stream>>>(Wv2, WtV);
  cvt_wt_kernel<<<(1024*512+255)/256, 256, 0, stream>>>(Ws2, WtS);

  // ================= Layer 2 =================
  hipMemsetAsync(den, 0, sizeof(float)*(size_t)NN*4, stream);

  {
    dim3 grid(8, MPAD/128);
    gemm_bf16_mfma<true><<<grid, 256, 0, stream>>>(hb, WtQ, bq2, q2b, NN);   // q2 bf16
    gemm_bf16_mfma<true><<<grid, 256, 0, stream>>>(hb, WtK, bk2, k2b, NN);   // k2 bf16
  }
  tproj1024_kernel<<<(NN*64+255)/256, 256, 0, stream>>>(q2b, We2, tproj);
  {
    dim3 ga(NB, 2);
    alpha_g1024<<<ga, 256, 0, stream>>>(q2b, k2b, ea, tproj, src, rowstart, eidx,
                                        alphab, amax);
  }
  ex_kernel<<<(NE*4+255)/256, 256, 0, stream>>>(alphab, amax, dst, den);
  {
    dim3 grid(8, MPAD/128);
    gemm_bf16_mfma<true><<<grid, 256, 0, stream>>>(hb, WtV, bv2, v2b, NN);   // v2 bf16 (q2b dead)
    gemm_bf16_mfma<false><<<grid, 256, 0, stream>>>(hb, WtS, bs2, s2, NN);   // s2 fp32 (k2b dead)
  }
  gather1024_kernel<<<NN, 256, 0, stream>>>(v2b, ea, We2, src, rowstart, eidx,
                                            alphab, den, s2);

  // ================= pooling + head (partial split-K + reduce) =================
  pool_kernel<<<(NB*256+255)/256, 256, 0, stream>>>(s2, g);   // C_a now dead -> P1/P2

  {
    dim3 gfp(256/64, (NB+63)/64, 8);
    sgemm_partial<<<gfp, 256, 0, stream>>>(fpb, Wfp, P2, NB, 256, 2048, 256, 0);
    reduce_add_kernel<<<(NB*256+255)/256, 256, 0, stream>>>(P2, bfp, fp, NB*256, 8, 255);
  }
  {
    dim3 g1(1024/64, (NB+63)/64, 4);
    sgemm_partial<<<g1, 256, 0, stream>>>(g, Wfin, P1, NB, 1024, 1024, 256, 0);
    dim3 g2(1024/64, (NB+63)/64, 1);
    sgemm_partial<<<g2, 256, 0, stream>>>(fp, Wfin + (size_t)1024*1024, P1, NB, 1024, 256, 256, 4);
    reduce_add_kernel<<<(NB*1024+255)/256, 256, 0, stream>>>(P1, bfin, out, NB*1024, 5, 1023);
  }
}

// Round 12
// 858.929 us; speedup vs baseline: 1.0386x; 1.0386x over previous
//
#include <hip/hip_runtime.h>
#include <cstdint>
#include <cstddef>

static constexpr int NN = 24000;   // nodes
static constexpr int NE = 96000;   // edges
static constexpr int NB = 1200;    // graphs
static constexpr int NPG = 20;     // nodes per graph
static constexpr int MPAD = 24064; // NN padded to 128

typedef __attribute__((ext_vector_type(8))) short bfv8;
typedef __attribute__((ext_vector_type(4))) float fv4;

// ---- ordered-uint mapping for float atomicMax (memset 0 == -inf) ----
__device__ __forceinline__ unsigned f2ord(float f){
  unsigned u = __float_as_uint(f);
  return (u & 0x80000000u) ? ~u : (u | 0x80000000u);
}
__device__ __forceinline__ float ord2f(unsigned u){
  return (u & 0x80000000u) ? __uint_as_float(u & 0x7FFFFFFFu)
                           : __uint_as_float(~u);
}
__device__ __forceinline__ unsigned short f2bf(float f){
  unsigned u = __float_as_uint(f);
  u += 0x7FFFu + ((u >> 16) & 1u);   // RNE
  return (unsigned short)(u >> 16);
}
__device__ __forceinline__ float bf2f(unsigned short s){
  return __uint_as_float(((unsigned)s) << 16);
}

// ---------------- CSR build ----------------
__global__ __launch_bounds__(256) void count_kernel(const int* __restrict__ dst,
                                                    unsigned* __restrict__ deg)
{
  int e = blockIdx.x*256 + threadIdx.x;
  if (e < NE) atomicAdd(&deg[dst[e]], 1u);
}

__global__ __launch_bounds__(1024) void scan_kernel(const unsigned* __restrict__ deg,
                                                    unsigned* __restrict__ rowstart)
{
  __shared__ unsigned s[1024];
  __shared__ unsigned carry_s;
  int tid = threadIdx.x;
  if (tid == 0) carry_s = 0;
  __syncthreads();
  for (int base = 0; base < NN; base += 1024){
    unsigned v = (base + tid < NN) ? deg[base + tid] : 0u;
    s[tid] = v;
    __syncthreads();
#pragma unroll
    for (int off = 1; off < 1024; off <<= 1){
      unsigned t = (tid >= off) ? s[tid - off] : 0u;
      __syncthreads();
      s[tid] += t;
      __syncthreads();
    }
    unsigned carry = carry_s;
    if (base + tid < NN) rowstart[base + tid] = carry + s[tid] - v;
    __syncthreads();
    if (tid == 0) carry_s = carry + s[1023];
    __syncthreads();
  }
  if (tid == 0) rowstart[NN] = carry_s;
}

__global__ __launch_bounds__(256) void scatter_kernel(const int* __restrict__ dst,
                                                      const unsigned* __restrict__ rowstart,
                                                      unsigned* __restrict__ cur,
                                                      int* __restrict__ eidx)
{
  int e = blockIdx.x*256 + threadIdx.x;
  if (e >= NE) return;
  int d = dst[e];
  unsigned p = rowstart[d] + atomicAdd(&cur[d], 1u);
  eidx[p] = e;
}

// ---------------- layer-1 node projections (K=9), two outputs per pass ----------------
template<bool BA, bool BB>
__global__ __launch_bounds__(256) void node_gemm_l1_pair(
    const float* __restrict__ x,
    const float* __restrict__ Wa, const float* __restrict__ ba,
    const float* __restrict__ Wb, const float* __restrict__ bb,
    void* __restrict__ outa, void* __restrict__ outb)
{
  int t = blockIdx.x*256 + threadIdx.x;
  if (t >= NN*512) return;
  int n = t >> 9, j = t & 511;
  float xr[9];
#pragma unroll
  for (int i=0;i<9;i++) xr[i] = x[n*9+i];
  float aa=ba[j], ab=bb[j];
#pragma unroll
  for (int i=0;i<9;i++){
    float xi = xr[i];
    aa += xi*Wa[i*512+j];
    ab += xi*Wb[i*512+j];
  }
  if (BA) ((unsigned short*)outa)[t] = f2bf(aa); else ((float*)outa)[t] = aa;
  if (BB) ((unsigned short*)outb)[t] = f2bf(ab); else ((float*)outb)[t] = ab;
}

// ---------------- t[n][h][c] = sum_{f in head h} q[n,f] * We[c,f]  (HC=512) ----------------
__global__ __launch_bounds__(256) void tproj512_kernel(
    const unsigned short* __restrict__ q, const float* __restrict__ We,
    float* __restrict__ t)
{
  int wave = (blockIdx.x*256 + threadIdx.x) >> 6;
  int lane = threadIdx.x & 63;
  if (wave >= NN) return;
  int off = lane*8;
  bfv8 qv = *reinterpret_cast<const bfv8*>(q + (size_t)wave*512 + off);
  float p0=0.f,p1=0.f,p2=0.f,p3=0.f;
#pragma unroll
  for (int j=0;j<8;j++){
    float qf = bf2f((unsigned short)qv[j]);
    int f = off + j;
    p0 += qf*We[f]; p1 += qf*We[512+f]; p2 += qf*We[1024+f]; p3 += qf*We[1536+f];
  }
#pragma unroll
  for (int o=8;o>=1;o>>=1){
    p0 += __shfl_xor(p0,o); p1 += __shfl_xor(p1,o);
    p2 += __shfl_xor(p2,o); p3 += __shfl_xor(p3,o);
  }
  if ((lane & 15) == 0){
    int h = lane >> 4;
    *reinterpret_cast<float4*>(t + (size_t)wave*16 + h*4) = make_float4(p0,p1,p2,p3);
  }
}

// ---------------- same for HC=1024 ----------------
__global__ __launch_bounds__(256) void tproj1024_kernel(
    const unsigned short* __restrict__ q, const float* __restrict__ We,
    float* __restrict__ t)
{
  int wave = (blockIdx.x*256 + threadIdx.x) >> 6;
  int lane = threadIdx.x & 63;
  if (wave >= NN) return;
  float p0=0.f,p1=0.f,p2=0.f,p3=0.f;
#pragma unroll
  for (int half=0; half<2; ++half){
    int off = lane*16 + half*8;
    bfv8 qv = *reinterpret_cast<const bfv8*>(q + (size_t)wave*1024 + off);
#pragma unroll
    for (int j=0;j<8;j++){
      float qf = bf2f((unsigned short)qv[j]);
      int f = off + j;
      p0 += qf*We[f]; p1 += qf*We[1024+f]; p2 += qf*We[2048+f]; p3 += qf*We[3072+f];
    }
  }
#pragma unroll
  for (int o=8;o>=1;o>>=1){
    p0 += __shfl_xor(p0,o); p1 += __shfl_xor(p1,o);
    p2 += __shfl_xor(p2,o); p3 += __shfl_xor(p3,o);
  }
  if ((lane & 15) == 0){
    int h = lane >> 4;
    *reinterpret_cast<float4*>(t + (size_t)wave*16 + h*4) = make_float4(p0,p1,p2,p3);
  }
}

// ---------------- L1 alpha (bf16 q/k, HC=512, tproj-factored): one wave per edge ----------------
__global__ __launch_bounds__(256) void alpha_tp512(
    const unsigned short* __restrict__ q, const unsigned short* __restrict__ k,
    const float* __restrict__ ea, const float* __restrict__ t,
    const int* __restrict__ src, const int* __restrict__ dst,
    float* __restrict__ alpha, unsigned* __restrict__ amax)
{
  int wave = (blockIdx.x*256 + threadIdx.x) >> 6;
  int lane = threadIdx.x & 63;
  if (wave >= NE) return;
  int e = wave;
  int s = src[e], d = dst[e];
  const float scale = 0.088388347648318447f;   // 1/sqrt(128)
  int off = lane*8;
  bfv8 qv = *reinterpret_cast<const bfv8*>(q + (size_t)d*512 + off);
  bfv8 kv = *reinterpret_cast<const bfv8*>(k + (size_t)s*512 + off);
  float part = 0.f;
#pragma unroll
  for (int j=0;j<8;j++)
    part += bf2f((unsigned short)qv[j]) * bf2f((unsigned short)kv[j]);
#pragma unroll
  for (int o=8; o>=1; o>>=1) part += __shfl_xor(part, o);  // per-16-lane group
  if ((lane & 15) == 0){
    int h = lane >> 4;
    float4 tv  = *reinterpret_cast<const float4*>(t + (size_t)d*16 + h*4);
    float4 eav = *reinterpret_cast<const float4*>(ea + (size_t)e*4);
    float a = (part + eav.x*tv.x + eav.y*tv.y + eav.z*tv.z + eav.w*tv.w)*scale;
    alpha[e*4+h] = a;
    atomicMax(&amax[d*4+h], f2ord(a));
  }
}

// ---------------- L2 alpha (bf16 q/k, HC=1024, tproj-factored): one wave per edge ----------------
__global__ __launch_bounds__(256) void alpha_tp1024(
    const unsigned short* __restrict__ q, const unsigned short* __restrict__ k,
    const float* __restrict__ ea, const float* __restrict__ t,
    const int* __restrict__ src, const int* __restrict__ dst,
    float* __restrict__ alpha, unsigned* __restrict__ amax)
{
  int wave = (blockIdx.x*256 + threadIdx.x) >> 6;
  int lane = threadIdx.x & 63;
  if (wave >= NE) return;
  int e = wave;
  int s = src[e], d = dst[e];
  const float scale = 1.0f/16.0f;   // 1/sqrt(256)
#pragma unroll
  for (int p=0;p<2;p++){
    int off = p*512 + lane*8;
    bfv8 qv = *reinterpret_cast<const bfv8*>(q + (size_t)d*1024 + off);
    bfv8 kv = *reinterpret_cast<const bfv8*>(k + (size_t)s*1024 + off);
    float part = 0.f;
#pragma unroll
    for (int j=0;j<8;j++)
      part += bf2f((unsigned short)qv[j]) * bf2f((unsigned short)kv[j]);
#pragma unroll
    for (int o=16; o>=1; o>>=1) part += __shfl_xor(part, o);  // reduce 32-lane half
    if ((lane & 31) == 0){
      int h = p*2 + (lane>>5);
      float4 tv  = *reinterpret_cast<const float4*>(t + (size_t)d*16 + h*4);
      float4 eav = *reinterpret_cast<const float4*>(ea + (size_t)e*4);
      float a = (part + eav.x*tv.x + eav.y*tv.y + eav.z*tv.z + eav.w*tv.w)*scale;
      alpha[e*4+h] = a;
      atomicMax(&amax[d*4+h], f2ord(a));
    }
  }
}

// ---------------- exp + denominator ----------------
__global__ __launch_bounds__(256) void ex_kernel(
    float* __restrict__ alpha, const unsigned* __restrict__ amax,
    const int* __restrict__ dst, float* __restrict__ den)
{
  int t = blockIdx.x*256 + threadIdx.x;
  if (t >= NE*4) return;
  int e = t>>2, h = t&3;
  int d = dst[e];
  float m = ord2f(amax[d*4+h]);
  float v = __expf(alpha[t]-m);
  alpha[t] = v;
  unsafeAtomicAdd(&den[d*4+h], v);
}

// ---------------- CSR gather L1: bf16 v, fp32 s1 init, bf16 relu'd output ----------------
__global__ __launch_bounds__(256) void gather512_kernel(
    const unsigned short* __restrict__ v, const float* __restrict__ ea,
    const float* __restrict__ We,
    const int* __restrict__ src,
    const unsigned* __restrict__ rowstart, const int* __restrict__ eidx,
    const float* __restrict__ exw, const float* __restrict__ den,
    const float* __restrict__ accin, unsigned short* __restrict__ hb)
{
  int n = blockIdx.x;
  int tid = threadIdx.x;
  int h = tid >> 6;
  int f2 = tid*2;
  unsigned p0 = rowstart[n], p1 = rowstart[n+1];
  float2 W0 = *reinterpret_cast<const float2*>(We + 0*512 + f2);
  float2 W1 = *reinterpret_cast<const float2*>(We + 1*512 + f2);
  float2 W2 = *reinterpret_cast<const float2*>(We + 2*512 + f2);
  float2 W3 = *reinterpret_cast<const float2*>(We + 3*512 + f2);
  float rdn = 1.0f / (den[n*4+h] + 1e-16f);
  float2 s = *reinterpret_cast<const float2*>(accin + (size_t)n*512 + f2);
  for (unsigned p = p0; p < p1; ++p){
    int e  = eidx[p];
    float w = exw[e*4+h] * rdn;
    float4 eav = *reinterpret_cast<const float4*>(ea + (size_t)e*4);
    ushort2 vv = *reinterpret_cast<const ushort2*>(v + (size_t)src[e]*512 + f2);
    float efx = eav.x*W0.x + eav.y*W1.x + eav.z*W2.x + eav.w*W3.x;
    float efy = eav.x*W0.y + eav.y*W1.y + eav.z*W2.y + eav.w*W3.y;
    s.x += w*(bf2f(vv.x) + efx);
    s.y += w*(bf2f(vv.y) + efy);
  }
  ushort2 o;
  o.x = f2bf(fmaxf(s.x, 0.0f));
  o.y = f2bf(fmaxf(s.y, 0.0f));
  *reinterpret_cast<ushort2*>(hb + (size_t)n*512 + f2) = o;
}

// ---------------- CSR gather L2: bf16 v, fp32 acc in-place ----------------
__global__ __launch_bounds__(256) void gather1024_kernel(
    const unsigned short* __restrict__ v, const float* __restrict__ ea,
    const float* __restrict__ We,
    const int* __restrict__ src,
    const unsigned* __restrict__ rowstart, const int* __restrict__ eidx,
    const float* __restrict__ exw, const float* __restrict__ den,
    float* __restrict__ acc)
{
  int n = blockIdx.x;
  int tid = threadIdx.x;
  int h = tid >> 6;
  int f4 = tid*4;
  unsigned p0 = rowstart[n], p1 = rowstart[n+1];
  float4 W0 = *reinterpret_cast<const float4*>(We + 0*1024 + f4);
  float4 W1 = *reinterpret_cast<const float4*>(We + 1*1024 + f4);
  float4 W2 = *reinterpret_cast<const float4*>(We + 2*1024 + f4);
  float4 W3 = *reinterpret_cast<const float4*>(We + 3*1024 + f4);
  float rdn = 1.0f / (den[n*4+h] + 1e-16f);
  float4 s = *reinterpret_cast<float4*>(acc + (size_t)n*1024 + f4);
  for (unsigned p = p0; p < p1; ++p){
    int e  = eidx[p];
    float w = exw[e*4+h] * rdn;
    float4 eav = *reinterpret_cast<const float4*>(ea + (size_t)e*4);
    ushort4 vv = *reinterpret_cast<const ushort4*>(v + (size_t)src[e]*1024 + f4);
    s.x += w*(bf2f(vv.x) + eav.x*W0.x + eav.y*W1.x + eav.z*W2.x + eav.w*W3.x);
    s.y += w*(bf2f(vv.y) + eav.x*W0.y + eav.y*W1.y + eav.z*W2.y + eav.w*W3.y);
    s.z += w*(bf2f(vv.z) + eav.x*W0.z + eav.y*W1.z + eav.z*W2.z + eav.w*W3.z);
    s.w += w*(bf2f(vv.w) + eav.x*W0.w + eav.y*W1.w + eav.z*W2.w + eav.w*W3.w);
  }
  *reinterpret_cast<float4*>(acc + (size_t)n*1024 + f4) = s;
}

// ---------------- W[512,1024] -> Wt[1024,512] bf16 ----------------
__global__ __launch_bounds__(256) void cvt_wt_kernel(const float* __restrict__ W,
                                                     unsigned short* __restrict__ Wt)
{
  int t = blockIdx.x*256 + threadIdx.x;
  if (t >= 1024*512) return;
  int n = t >> 9, k = t & 511;
  Wt[t] = f2bf(W[k*1024 + n]);
}

// ---------------- bf16 MFMA GEMM: out[M,1024] = A[MPAD,512]@Wt^T + bias ----------------
template<bool BOUT>
__global__ __launch_bounds__(256) void gemm_bf16_mfma(
    const unsigned short* __restrict__ A,
    const unsigned short* __restrict__ B,   // Wt
    const float* __restrict__ bias,
    void* __restrict__ Cout, int M)
{
  constexpr int K = 512, N = 1024;
  __shared__ unsigned short As[128*32];
  __shared__ unsigned short Bs[128*32];
  int tid  = threadIdx.x;
  int wid  = tid >> 6, lane = tid & 63;
  int wr   = wid >> 1, wc = wid & 1;
  int bm   = blockIdx.y * 128, bn = blockIdx.x * 128;
  int l15  = lane & 15, kg = lane >> 4;

  int r0 = (wid*2+0)*16 + (lane>>2);
  int r1 = (wid*2+1)*16 + (lane>>2);
  int s0 = lane & 3;
  int kc0 = s0 ^ ((r0>>1)&3);
  int kc1 = s0 ^ ((r1>>1)&3);
  unsigned short* ldsA0 = As + (wid*2+0)*512;
  unsigned short* ldsA1 = As + (wid*2+1)*512;
  unsigned short* ldsB0 = Bs + (wid*2+0)*512;
  unsigned short* ldsB1 = Bs + (wid*2+1)*512;

  fv4 acc[4][4];
#pragma unroll
  for (int m=0;m<4;m++)
#pragma unroll
    for (int n=0;n<4;n++) acc[m][n] = (fv4){0.f,0.f,0.f,0.f};

  for (int k0 = 0; k0 < K; k0 += 32){
    __syncthreads();
    __builtin_amdgcn_global_load_lds(
        (const __attribute__((address_space(1))) void*)(A + (size_t)(bm+r0)*K + k0 + kc0*8),
        (__attribute__((address_space(3))) void*)ldsA0, 16, 0, 0);
    __builtin_amdgcn_global_load_lds(
        (const __attribute__((address_space(1))) void*)(A + (size_t)(bm+r1)*K + k0 + kc1*8),
        (__attribute__((address_space(3))) void*)ldsA1, 16, 0, 0);
    __builtin_amdgcn_global_load_lds(
        (const __attribute__((address_space(1))) void*)(B + (size_t)(bn+r0)*K + k0 + kc0*8),
        (__attribute__((address_space(3))) void*)ldsB0, 16, 0, 0);
    __builtin_amdgcn_global_load_lds(
        (const __attribute__((address_space(1))) void*)(B + (size_t)(bn+r1)*K + k0 + kc1*8),
        (__attribute__((address_space(3))) void*)ldsB1, 16, 0, 0);
    __syncthreads();
    bfv8 af[4], bfr[4];
#pragma unroll
    for (int m=0;m<4;m++){
      int r  = wr*64 + m*16 + l15;
      int sl = kg ^ ((r>>1)&3);
      af[m] = *reinterpret_cast<const bfv8*>(reinterpret_cast<char*>(As) + r*64 + sl*16);
    }
#pragma unroll
    for (int n=0;n<4;n++){
      int r  = wc*64 + n*16 + l15;
      int sl = kg ^ ((r>>1)&3);
      bfr[n] = *reinterpret_cast<const bfv8*>(reinterpret_cast<char*>(Bs) + r*64 + sl*16);
    }
#pragma unroll
    for (int m=0;m<4;m++)
#pragma unroll
      for (int n=0;n<4;n++)
        acc[m][n] = __builtin_amdgcn_mfma_f32_16x16x32_bf16(af[m], bfr[n], acc[m][n], 0, 0, 0);
  }
#pragma unroll
  for (int m=0;m<4;m++){
#pragma unroll
    for (int n=0;n<4;n++){
      int col = bn + wc*64 + n*16 + l15;
      float bcol = bias[col];
#pragma unroll
      for (int r=0;r<4;r++){
        int row = bm + wr*64 + m*16 + (lane>>4)*4 + r;
        if (row < M){
          float val = acc[m][n][r] + bcol;
          if (BOUT) ((unsigned short*)Cout)[(size_t)row*N + col] = f2bf(val);
          else      ((float*)Cout)[(size_t)row*N + col] = val;
        }
      }
    }
  }
}

// ---------------- split-K fp32 GEMM to partial slabs (no atomics) ----------------
__global__ __launch_bounds__(256) void sgemm_partial(
    const float* __restrict__ A, const float* __restrict__ W,
    float* __restrict__ P, int M, int N, int K, int kchunk, int zoff)
{
  __shared__ float As[32][68];
  __shared__ __align__(16) float Bs[32][64];
  int tid = threadIdx.x;
  int bm = blockIdx.y*64, bn = blockIdx.x*64;
  int kbeg = blockIdx.z*kchunk;
  int kend = min(kbeg + kchunk, K);
  float* Pz = P + (size_t)(zoff + blockIdx.z)*M*N;
  int ty = tid >> 4, tx = tid & 15;
  float acc[4][4] = {};
  for (int k0 = kbeg; k0 < kend; k0 += 32){
#pragma unroll
    for (int i=0;i<2;i++){
      int lin = tid + i*256;
      int r = lin >> 3;
      int kq = (lin & 7) * 4;
      float4 av = make_float4(0.f,0.f,0.f,0.f);
      int row = bm + r;
      if (row < M) av = *reinterpret_cast<const float4*>(A + (size_t)row*K + k0 + kq);
      As[kq+0][r]=av.x; As[kq+1][r]=av.y; As[kq+2][r]=av.z; As[kq+3][r]=av.w;
    }
#pragma unroll
    for (int i=0;i<2;i++){
      int lin = tid + i*256;
      int kr = lin >> 4;
      int c4 = (lin & 15) * 4;
      float4 wv = *reinterpret_cast<const float4*>(W + (size_t)(k0+kr)*N + bn + c4);
      *reinterpret_cast<float4*>(&Bs[kr][c4]) = wv;
    }
    __syncthreads();
#pragma unroll
    for (int kk=0;kk<32;kk++){
      float a[4], b[4];
#pragma unroll
      for (int i=0;i<4;i++) a[i] = As[kk][ty*4+i];
#pragma unroll
      for (int j=0;j<4;j++) b[j] = Bs[kk][tx*4+j];
#pragma unroll
      for (int i=0;i<4;i++)
#pragma unroll
        for (int j=0;j<4;j++) acc[i][j] += a[i]*b[j];
    }
    __syncthreads();
  }
#pragma unroll
  for (int i=0;i<4;i++){
    int row = bm + ty*4 + i;
    if (row >= M) break;
#pragma unroll
    for (int j=0;j<4;j++)
      Pz[(size_t)row*N + bn + tx*4 + j] = acc[i][j];
  }
}

// ---------------- O[t] = bias[t&nmask] + sum_z P[z][t] ----------------
__global__ __launch_bounds__(256) void reduce_add_kernel(
    const float* __restrict__ P, const float* __restrict__ bias,
    float* __restrict__ O, int total, int nz, int nmask)
{
  int t = blockIdx.x*256 + threadIdx.x;
  if (t >= total) return;
  float s = bias[t & nmask];
  for (int z = 0; z < nz; ++z) s += P[(size_t)z*total + t];
  O[t] = s;
}

// ---------------- mean pool (float4) ----------------
__global__ __launch_bounds__(256) void pool_kernel(const float* __restrict__ h2,
                                                   float* __restrict__ g)
{
  int t = blockIdx.x*256 + threadIdx.x;
  if (t >= NB*256) return;
  int b = t >> 8, f4 = (t & 255) * 4;
  float4 s = make_float4(0.f,0.f,0.f,0.f);
#pragma unroll
  for (int i=0;i<NPG;i++){
    float4 v = *reinterpret_cast<const float4*>(h2 + (size_t)(b*NPG+i)*1024 + f4);
    s.x += v.x; s.y += v.y; s.z += v.z; s.w += v.w;
  }
  s.x *= (1.0f/NPG); s.y *= (1.0f/NPG); s.z *= (1.0f/NPG); s.w *= (1.0f/NPG);
  *reinterpret_cast<float4*>(g + (size_t)b*1024 + f4) = s;
}

extern "C" void kernel_launch(void* const* d_in, const int* in_sizes, int n_in,
                              void* d_out, int out_size, void* d_ws, size_t ws_size,
                              hipStream_t stream)
{
  const float* x    = (const float*)d_in[0];
  const int*   ei   = (const int*)d_in[1];
  const float* ea   = (const float*)d_in[2];
  const float* fpb  = (const float*)d_in[4];
  const float* Wq1  = (const float*)d_in[5];  const float* bq1 = (const float*)d_in[6];
  const float* Wk1  = (const float*)d_in[7];  const float* bk1 = (const float*)d_in[8];
  const float* Wv1  = (const float*)d_in[9];  const float* bv1 = (const float*)d_in[10];
  const float* We1  = (const float*)d_in[11];
  const float* Ws1  = (const float*)d_in[12]; const float* bs1 = (const float*)d_in[13];
  const float* Wq2  = (const float*)d_in[14]; const float* bq2 = (const float*)d_in[15];
  const float* Wk2  = (const float*)d_in[16]; const float* bk2 = (const float*)d_in[17];
  const float* Wv2  = (const float*)d_in[18]; const float* bv2 = (const float*)d_in[19];
  const float* We2  = (const float*)d_in[20];
  const float* Ws2  = (const float*)d_in[21]; const float* bs2 = (const float*)d_in[22];
  const float* Wfp  = (const float*)d_in[23]; const float* bfp = (const float*)d_in[24];
  const float* Wfin = (const float*)d_in[25]; const float* bfin= (const float*)d_in[26];
  const int* src = ei;
  const int* dst = ei + NE;
  float* out = (float*)d_out;

  // ---- workspace layout (~257 MB peak, time-disjoint aliasing) ----
  const size_t F512  = (size_t)NN*512;
  const size_t F1024 = (size_t)NN*1024;
  float* base = (float*)d_ws;
  float* C_a = base;                    // q1b/v1b; q2b/v2b (bf16); hb at +F1024 ushorts; P1/P2
  float* C_b = base + F1024;            // k2b (bf16); s2/acc2 fp32
  float* H   = base + 2*F1024;          // k1b (bf16); s1 fp32; later Wt (bf16)
  unsigned short* q1b = (unsigned short*)C_a;        // [NN,512]
  unsigned short* v1b = (unsigned short*)C_a;        // [NN,512] (q1b dead)
  unsigned short* k1b = (unsigned short*)H;          // [NN,512]
  float*          s1  = H;                           // [NN,512] fp32 (k1b dead)
  unsigned short* hb  = (unsigned short*)C_a + F1024;   // [MPAD,512] bf16
  unsigned short* q2b = (unsigned short*)C_a;        // [NN,1024] bf16
  unsigned short* k2b = (unsigned short*)C_b;        // [NN,1024] bf16
  unsigned short* v2b = (unsigned short*)C_a;        // [NN,1024] bf16 (q2b dead)
  float*          s2  = C_b;                         // [NN,1024] fp32 (k2b dead)
  unsigned short* WtQ = (unsigned short*)H;          // 4 x [1024,512] bf16 (s1 dead)
  unsigned short* WtK = WtQ + (size_t)1024*512;
  unsigned short* WtV = WtK + (size_t)1024*512;
  unsigned short* WtS = WtV + (size_t)1024*512;
  float* P1 = C_a;                            // 5 x [NB*1024]
  float* P2 = C_a + 5*(size_t)NB*1024;        // 8 x [NB*256]

  float* tail = base + 2*F1024 + F512;
  float*    alphab   = tail;                                  // NE*4 (scores -> exp)
  unsigned* amax     = (unsigned*)(alphab + (size_t)NE*4);    // NN*4
  float*    den      = (float*)(amax + (size_t)NN*4);         // NN*4
  unsigned* deg      = (unsigned*)(den + (size_t)NN*4);       // NN
  unsigned* cur      = deg + NN;                              // NN
  unsigned* rowstart = cur + NN;                              // NN+1
  int*      eidx     = (int*)(rowstart + NN + 1);             // NE
  float*    g        = (float*)(eidx + NE);                   // NB*1024
  float*    fp       = g + (size_t)NB*1024;                   // NB*256
  float*    tproj    = fp + (size_t)NB*256;                   // NN*16 (t1 then t2)

  // ================= CSR build =================
  hipMemsetAsync(deg, 0, sizeof(unsigned)*NN, stream);
  hipMemsetAsync(cur, 0, sizeof(unsigned)*NN, stream);
  count_kernel<<<(NE+255)/256, 256, 0, stream>>>(dst, deg);
  scan_kernel<<<1, 1024, 0, stream>>>(deg, rowstart);
  scatter_kernel<<<(NE+255)/256, 256, 0, stream>>>(dst, rowstart, cur, eidx);

  // ================= Layer 1 =================
  hipMemsetAsync(amax, 0, sizeof(unsigned)*(size_t)NN*4, stream);
  hipMemsetAsync(den,  0, sizeof(float)*(size_t)NN*4, stream);

  node_gemm_l1_pair<true,true><<<(NN*512+255)/256, 256, 0, stream>>>(
      x, Wq1,bq1, Wk1,bk1, q1b, k1b);
  tproj512_kernel<<<(NN*64+255)/256, 256, 0, stream>>>(q1b, We1, tproj);
  alpha_tp512<<<NE/4, 256, 0, stream>>>(q1b, k1b, ea, tproj, src, dst, alphab, amax);
  ex_kernel<<<(NE*4+255)/256, 256, 0, stream>>>(alphab, amax, dst, den);
  node_gemm_l1_pair<true,false><<<(NN*512+255)/256, 256, 0, stream>>>(
      x, Wv1,bv1, Ws1,bs1, v1b, s1);
  gather512_kernel<<<NN, 256, 0, stream>>>(v1b, ea, We1, src, rowstart, eidx,
                                           alphab, den, s1, hb);
  hipMemsetAsync(hb + F512, 0, (size_t)(MPAD-NN)*512*sizeof(unsigned short), stream);

  // ================= weights to bf16 (H free: s1 dead) =================
  cvt_wt_kernel<<<(1024*512+255)/256, 256, 0, stream>>>(Wq2, WtQ);
  cvt_wt_kernel<<<(1024*512+255)/256, 256, 0, stream>>>(Wk2, WtK);
  cvt_wt_kernel<<<(1024*512+255)/256, 256, 0, stream>>>(Wv2, WtV);
  cvt_wt_kernel<<<(1024*512+255)/256, 256, 0, stream>>>(Ws2, WtS);

  // ================= Layer 2 =================
  hipMemsetAsync(amax, 0, sizeof(unsigned)*(size_t)NN*4, stream);
  hipMemsetAsync(den,  0, sizeof(float)*(size_t)NN*4, stream);

  {
    dim3 grid(8, MPAD/128);
    gemm_bf16_mfma<true><<<grid, 256, 0, stream>>>(hb, WtQ, bq2, q2b, NN);   // q2 bf16
    gemm_bf16_mfma<true><<<grid, 256, 0, stream>>>(hb, WtK, bk2, k2b, NN);   // k2 bf16
  }
  tproj1024_kernel<<<(NN*64+255)/256, 256, 0, stream>>>(q2b, We2, tproj);
  alpha_tp1024<<<NE/4, 256, 0, stream>>>(q2b, k2b, ea, tproj, src, dst, alphab, amax);
  ex_kernel<<<(NE*4+255)/256, 256, 0, stream>>>(alphab, amax, dst, den);
  {
    dim3 grid(8, MPAD/128);
    gemm_bf16_mfma<true><<<grid, 256, 0, stream>>>(hb, WtV, bv2, v2b, NN);   // v2 bf16 (q2b dead)
    gemm_bf16_mfma<false><<<grid, 256, 0, stream>>>(hb, WtS, bs2, s2, NN);   // s2 fp32 (k2b dead)
  }
  gather1024_kernel<<<NN, 256, 0, stream>>>(v2b, ea, We2, src, rowstart, eidx,
                                            alphab, den, s2);

  // ================= pooling + head (partial split-K + reduce) =================
  pool_kernel<<<(NB*256+255)/256, 256, 0, stream>>>(s2, g);   // C_a now dead -> P1/P2

  {
    dim3 gfp(256/64, (NB+63)/64, 8);
    sgemm_partial<<<gfp, 256, 0, stream>>>(fpb, Wfp, P2, NB, 256, 2048, 256, 0);
    reduce_add_kernel<<<(NB*256+255)/256, 256, 0, stream>>>(P2, bfp, fp, NB*256, 8, 255);
  }
  {
    dim3 g1(1024/64, (NB+63)/64, 4);
    sgemm_partial<<<g1, 256, 0, stream>>>(g, Wfin, P1, NB, 1024, 1024, 256, 0);
    dim3 g2(1024/64, (NB+63)/64, 1);
    sgemm_partial<<<g2, 256, 0, stream>>>(fp, Wfin + (size_t)1024*1024, P1, NB, 1024, 256, 256, 4);
    reduce_add_kernel<<<(NB*1024+255)/256, 256, 0, stream>>>(P1, bfin, out, NB*1024, 5, 1023);
  }
}

// Round 13
// 816.311 us; speedup vs baseline: 1.0928x; 1.0522x over previous
//
#include <hip/hip_runtime.h>
#include <cstdint>
#include <cstddef>

static constexpr int NN = 24000;   // nodes
static constexpr int NE = 96000;   // edges
static constexpr int NB = 1200;    // graphs
static constexpr int NPG = 20;     // nodes per graph
static constexpr int MPAD = 24064; // NN padded to 128

typedef __attribute__((ext_vector_type(8))) short bfv8;
typedef __attribute__((ext_vector_type(4))) float fv4;

// ---- ordered-uint mapping for float atomicMax (memset 0 == -inf) ----
__device__ __forceinline__ unsigned f2ord(float f){
  unsigned u = __float_as_uint(f);
  return (u & 0x80000000u) ? ~u : (u | 0x80000000u);
}
__device__ __forceinline__ float ord2f(unsigned u){
  return (u & 0x80000000u) ? __uint_as_float(u & 0x7FFFFFFFu)
                           : __uint_as_float(~u);
}
__device__ __forceinline__ unsigned short f2bf(float f){
  unsigned u = __float_as_uint(f);
  u += 0x7FFFu + ((u >> 16) & 1u);   // RNE
  return (unsigned short)(u >> 16);
}
__device__ __forceinline__ float bf2f(unsigned short s){
  return __uint_as_float(((unsigned)s) << 16);
}

// ---------------- CSR build ----------------
__global__ __launch_bounds__(256) void count_kernel(const int* __restrict__ dst,
                                                    unsigned* __restrict__ deg)
{
  int e = blockIdx.x*256 + threadIdx.x;
  if (e < NE) atomicAdd(&deg[dst[e]], 1u);
}

__global__ __launch_bounds__(1024) void scan_kernel(const unsigned* __restrict__ deg,
                                                    unsigned* __restrict__ rowstart)
{
  __shared__ unsigned s[1024];
  __shared__ unsigned carry_s;
  int tid = threadIdx.x;
  if (tid == 0) carry_s = 0;
  __syncthreads();
  for (int base = 0; base < NN; base += 1024){
    unsigned v = (base + tid < NN) ? deg[base + tid] : 0u;
    s[tid] = v;
    __syncthreads();
#pragma unroll
    for (int off = 1; off < 1024; off <<= 1){
      unsigned t = (tid >= off) ? s[tid - off] : 0u;
      __syncthreads();
      s[tid] += t;
      __syncthreads();
    }
    unsigned carry = carry_s;
    if (base + tid < NN) rowstart[base + tid] = carry + s[tid] - v;
    __syncthreads();
    if (tid == 0) carry_s = carry + s[1023];
    __syncthreads();
  }
  if (tid == 0) rowstart[NN] = carry_s;
}

__global__ __launch_bounds__(256) void scatter_kernel(const int* __restrict__ dst,
                                                      const unsigned* __restrict__ rowstart,
                                                      unsigned* __restrict__ cur,
                                                      int* __restrict__ eidx)
{
  int e = blockIdx.x*256 + threadIdx.x;
  if (e >= NE) return;
  int d = dst[e];
  unsigned p = rowstart[d] + atomicAdd(&cur[d], 1u);
  eidx[p] = e;
}

// ---------------- layer-1 node projections (K=9), two outputs per pass ----------------
template<bool BA, bool BB>
__global__ __launch_bounds__(256) void node_gemm_l1_pair(
    const float* __restrict__ x,
    const float* __restrict__ Wa, const float* __restrict__ ba,
    const float* __restrict__ Wb, const float* __restrict__ bb,
    void* __restrict__ outa, void* __restrict__ outb)
{
  int t = blockIdx.x*256 + threadIdx.x;
  if (t >= NN*512) return;
  int n = t >> 9, j = t & 511;
  float xr[9];
#pragma unroll
  for (int i=0;i<9;i++) xr[i] = x[n*9+i];
  float aa=ba[j], ab=bb[j];
#pragma unroll
  for (int i=0;i<9;i++){
    float xi = xr[i];
    aa += xi*Wa[i*512+j];
    ab += xi*Wb[i*512+j];
  }
  if (BA) ((unsigned short*)outa)[t] = f2bf(aa); else ((float*)outa)[t] = aa;
  if (BB) ((unsigned short*)outb)[t] = f2bf(ab); else ((float*)outb)[t] = ab;
}

// ---------------- L1 attention scores (bf16 q/k, HC=512): one wave per edge ----------------
__global__ __launch_bounds__(256) void alpha_bf16_hc512(
    const unsigned short* __restrict__ q, const unsigned short* __restrict__ k,
    const float* __restrict__ ea, const float* __restrict__ We,
    const int* __restrict__ src, const int* __restrict__ dst,
    float* __restrict__ alpha, unsigned* __restrict__ amax)
{
  int wave = (blockIdx.x*256 + threadIdx.x) >> 6;
  int lane = threadIdx.x & 63;
  if (wave >= NE) return;
  int e = wave;
  int s = src[e], d = dst[e];
  float ea0=ea[e*4+0], ea1=ea[e*4+1], ea2=ea[e*4+2], ea3=ea[e*4+3];
  const float scale = 0.088388347648318447f;   // 1/sqrt(128)
  int off = lane*8;
  bfv8 qv = *reinterpret_cast<const bfv8*>(q + (size_t)d*512 + off);
  bfv8 kv = *reinterpret_cast<const bfv8*>(k + (size_t)s*512 + off);
  float part = 0.f;
#pragma unroll
  for (int j=0;j<8;j++){
    int f = off + j;
    float ef = ea0*We[f] + ea1*We[512+f] + ea2*We[1024+f] + ea3*We[1536+f];
    part += bf2f((unsigned short)qv[j]) * (bf2f((unsigned short)kv[j]) + ef);
  }
#pragma unroll
  for (int o=8; o>=1; o>>=1) part += __shfl_xor(part, o);  // per-16-lane group
  if ((lane & 15) == 0){
    int h = lane >> 4;
    float a = part*scale;
    alpha[e*4+h] = a;
    atomicMax(&amax[d*4+h], f2ord(a));
  }
}

// ---------------- L2 attention scores (bf16 q/k, HC=1024): one wave per edge ----------------
__global__ __launch_bounds__(256) void alpha_bf16_hc1024(
    const unsigned short* __restrict__ q, const unsigned short* __restrict__ k,
    const float* __restrict__ ea, const float* __restrict__ We,
    const int* __restrict__ src, const int* __restrict__ dst,
    float* __restrict__ alpha, unsigned* __restrict__ amax)
{
  int wave = (blockIdx.x*256 + threadIdx.x) >> 6;
  int lane = threadIdx.x & 63;
  if (wave >= NE) return;
  int e = wave;
  int s = src[e], d = dst[e];
  float ea0=ea[e*4+0], ea1=ea[e*4+1], ea2=ea[e*4+2], ea3=ea[e*4+3];
  const float scale = 1.0f/16.0f;   // 1/sqrt(256)
#pragma unroll
  for (int p=0;p<2;p++){
    int off = p*512 + lane*8;
    bfv8 qv = *reinterpret_cast<const bfv8*>(q + (size_t)d*1024 + off);
    bfv8 kv = *reinterpret_cast<const bfv8*>(k + (size_t)s*1024 + off);
    float part = 0.f;
#pragma unroll
    for (int j=0;j<8;j++){
      int f = off + j;
      float ef = ea0*We[f] + ea1*We[1024+f] + ea2*We[2048+f] + ea3*We[3072+f];
      part += bf2f((unsigned short)qv[j]) * (bf2f((unsigned short)kv[j]) + ef);
    }
#pragma unroll
    for (int o=16; o>=1; o>>=1) part += __shfl_xor(part, o);  // reduce 32-lane half
    if ((lane & 31) == 0){
      int h = p*2 + (lane>>5);
      float a = part*scale;
      alpha[e*4+h] = a;
      atomicMax(&amax[d*4+h], f2ord(a));
    }
  }
}

// ---------------- exp + denominator ----------------
__global__ __launch_bounds__(256) void ex_kernel(
    float* __restrict__ alpha, const unsigned* __restrict__ amax,
    const int* __restrict__ dst, float* __restrict__ den)
{
  int t = blockIdx.x*256 + threadIdx.x;
  if (t >= NE*4) return;
  int e = t>>2, h = t&3;
  int d = dst[e];
  float m = ord2f(amax[d*4+h]);
  float v = __expf(alpha[t]-m);
  alpha[t] = v;
  unsafeAtomicAdd(&den[d*4+h], v);
}

// ---------------- CSR gather L1: bf16 v, bf16 s1 init, bf16 relu'd output ----------------
__global__ __launch_bounds__(256) void gather512_kernel(
    const unsigned short* __restrict__ v, const float* __restrict__ ea,
    const float* __restrict__ We,
    const int* __restrict__ src,
    const unsigned* __restrict__ rowstart, const int* __restrict__ eidx,
    const float* __restrict__ exw, const float* __restrict__ den,
    const unsigned short* __restrict__ accin, unsigned short* __restrict__ hb)
{
  int n = blockIdx.x;
  int tid = threadIdx.x;
  int h = tid >> 6;
  int f2 = tid*2;
  unsigned p0 = rowstart[n], p1 = rowstart[n+1];
  float2 W0 = *reinterpret_cast<const float2*>(We + 0*512 + f2);
  float2 W1 = *reinterpret_cast<const float2*>(We + 1*512 + f2);
  float2 W2 = *reinterpret_cast<const float2*>(We + 2*512 + f2);
  float2 W3 = *reinterpret_cast<const float2*>(We + 3*512 + f2);
  float rdn = 1.0f / (den[n*4+h] + 1e-16f);
  ushort2 a0 = *reinterpret_cast<const ushort2*>(accin + (size_t)n*512 + f2);
  float2 s = make_float2(bf2f(a0.x), bf2f(a0.y));
  for (unsigned p = p0; p < p1; ++p){
    int e  = eidx[p];
    float w = exw[e*4+h] * rdn;
    float4 eav = *reinterpret_cast<const float4*>(ea + (size_t)e*4);
    ushort2 vv = *reinterpret_cast<const ushort2*>(v + (size_t)src[e]*512 + f2);
    float efx = eav.x*W0.x + eav.y*W1.x + eav.z*W2.x + eav.w*W3.x;
    float efy = eav.x*W0.y + eav.y*W1.y + eav.z*W2.y + eav.w*W3.y;
    s.x += w*(bf2f(vv.x) + efx);
    s.y += w*(bf2f(vv.y) + efy);
  }
  ushort2 o;
  o.x = f2bf(fmaxf(s.x, 0.0f));
  o.y = f2bf(fmaxf(s.y, 0.0f));
  *reinterpret_cast<ushort2*>(hb + (size_t)n*512 + f2) = o;
}

// ---------------- CSR gather L2: bf16 v, bf16 acc RMW (fp32 accumulate) ----------------
__global__ __launch_bounds__(256) void gather1024_kernel(
    const unsigned short* __restrict__ v, const float* __restrict__ ea,
    const float* __restrict__ We,
    const int* __restrict__ src,
    const unsigned* __restrict__ rowstart, const int* __restrict__ eidx,
    const float* __restrict__ exw, const float* __restrict__ den,
    unsigned short* __restrict__ acc)
{
  int n = blockIdx.x;
  int tid = threadIdx.x;
  int h = tid >> 6;
  int f4 = tid*4;
  unsigned p0 = rowstart[n], p1 = rowstart[n+1];
  float4 W0 = *reinterpret_cast<const float4*>(We + 0*1024 + f4);
  float4 W1 = *reinterpret_cast<const float4*>(We + 1*1024 + f4);
  float4 W2 = *reinterpret_cast<const float4*>(We + 2*1024 + f4);
  float4 W3 = *reinterpret_cast<const float4*>(We + 3*1024 + f4);
  float rdn = 1.0f / (den[n*4+h] + 1e-16f);
  ushort4 a0 = *reinterpret_cast<const ushort4*>(acc + (size_t)n*1024 + f4);
  float4 s = make_float4(bf2f(a0.x), bf2f(a0.y), bf2f(a0.z), bf2f(a0.w));
  for (unsigned p = p0; p < p1; ++p){
    int e  = eidx[p];
    float w = exw[e*4+h] * rdn;
    float4 eav = *reinterpret_cast<const float4*>(ea + (size_t)e*4);
    ushort4 vv = *reinterpret_cast<const ushort4*>(v + (size_t)src[e]*1024 + f4);
    s.x += w*(bf2f(vv.x) + eav.x*W0.x + eav.y*W1.x + eav.z*W2.x + eav.w*W3.x);
    s.y += w*(bf2f(vv.y) + eav.x*W0.y + eav.y*W1.y + eav.z*W2.y + eav.w*W3.y);
    s.z += w*(bf2f(vv.z) + eav.x*W0.z + eav.y*W1.z + eav.z*W2.z + eav.w*W3.z);
    s.w += w*(bf2f(vv.w) + eav.x*W0.w + eav.y*W1.w + eav.z*W2.w + eav.w*W3.w);
  }
  ushort4 o;
  o.x = f2bf(s.x); o.y = f2bf(s.y); o.z = f2bf(s.z); o.w = f2bf(s.w);
  *reinterpret_cast<ushort4*>(acc + (size_t)n*1024 + f4) = o;
}

// ---------------- W[512,1024] -> Wt[1024,512] bf16 ----------------
__global__ __launch_bounds__(256) void cvt_wt_kernel(const float* __restrict__ W,
                                                     unsigned short* __restrict__ Wt)
{
  int t = blockIdx.x*256 + threadIdx.x;
  if (t >= 1024*512) return;
  int n = t >> 9, k = t & 511;
  Wt[t] = f2bf(W[k*1024 + n]);
}

// ---------------- bf16 MFMA GEMM: out[M,1024] = A[MPAD,512]@Wt^T + bias ----------------
template<bool BOUT>
__global__ __launch_bounds__(256) void gemm_bf16_mfma(
    const unsigned short* __restrict__ A,
    const unsigned short* __restrict__ B,   // Wt
    const float* __restrict__ bias,
    void* __restrict__ Cout, int M)
{
  constexpr int K = 512, N = 1024;
  __shared__ unsigned short As[128*32];
  __shared__ unsigned short Bs[128*32];
  int tid  = threadIdx.x;
  int wid  = tid >> 6, lane = tid & 63;
  int wr   = wid >> 1, wc = wid & 1;
  int bm   = blockIdx.y * 128, bn = blockIdx.x * 128;
  int l15  = lane & 15, kg = lane >> 4;

  int r0 = (wid*2+0)*16 + (lane>>2);
  int r1 = (wid*2+1)*16 + (lane>>2);
  int s0 = lane & 3;
  int kc0 = s0 ^ ((r0>>1)&3);
  int kc1 = s0 ^ ((r1>>1)&3);
  unsigned short* ldsA0 = As + (wid*2+0)*512;
  unsigned short* ldsA1 = As + (wid*2+1)*512;
  unsigned short* ldsB0 = Bs + (wid*2+0)*512;
  unsigned short* ldsB1 = Bs + (wid*2+1)*512;

  fv4 acc[4][4];
#pragma unroll
  for (int m=0;m<4;m++)
#pragma unroll
    for (int n=0;n<4;n++) acc[m][n] = (fv4){0.f,0.f,0.f,0.f};

  for (int k0 = 0; k0 < K; k0 += 32){
    __syncthreads();
    __builtin_amdgcn_global_load_lds(
        (const __attribute__((address_space(1))) void*)(A + (size_t)(bm+r0)*K + k0 + kc0*8),
        (__attribute__((address_space(3))) void*)ldsA0, 16, 0, 0);
    __builtin_amdgcn_global_load_lds(
        (const __attribute__((address_space(1))) void*)(A + (size_t)(bm+r1)*K + k0 + kc1*8),
        (__attribute__((address_space(3))) void*)ldsA1, 16, 0, 0);
    __builtin_amdgcn_global_load_lds(
        (const __attribute__((address_space(1))) void*)(B + (size_t)(bn+r0)*K + k0 + kc0*8),
        (__attribute__((address_space(3))) void*)ldsB0, 16, 0, 0);
    __builtin_amdgcn_global_load_lds(
        (const __attribute__((address_space(1))) void*)(B + (size_t)(bn+r1)*K + k0 + kc1*8),
        (__attribute__((address_space(3))) void*)ldsB1, 16, 0, 0);
    __syncthreads();
    bfv8 af[4], bfr[4];
#pragma unroll
    for (int m=0;m<4;m++){
      int r  = wr*64 + m*16 + l15;
      int sl = kg ^ ((r>>1)&3);
      af[m] = *reinterpret_cast<const bfv8*>(reinterpret_cast<char*>(As) + r*64 + sl*16);
    }
#pragma unroll
    for (int n=0;n<4;n++){
      int r  = wc*64 + n*16 + l15;
      int sl = kg ^ ((r>>1)&3);
      bfr[n] = *reinterpret_cast<const bfv8*>(reinterpret_cast<char*>(Bs) + r*64 + sl*16);
    }
#pragma unroll
    for (int m=0;m<4;m++)
#pragma unroll
      for (int n=0;n<4;n++)
        acc[m][n] = __builtin_amdgcn_mfma_f32_16x16x32_bf16(af[m], bfr[n], acc[m][n], 0, 0, 0);
  }
#pragma unroll
  for (int m=0;m<4;m++){
#pragma unroll
    for (int n=0;n<4;n++){
      int col = bn + wc*64 + n*16 + l15;
      float bcol = bias[col];
#pragma unroll
      for (int r=0;r<4;r++){
        int row = bm + wr*64 + m*16 + (lane>>4)*4 + r;
        if (row < M){
          float val = acc[m][n][r] + bcol;
          if (BOUT) ((unsigned short*)Cout)[(size_t)row*N + col] = f2bf(val);
          else      ((float*)Cout)[(size_t)row*N + col] = val;
        }
      }
    }
  }
}

// ---------------- split-K fp32 GEMM to partial slabs (no atomics) ----------------
__global__ __launch_bounds__(256) void sgemm_partial(
    const float* __restrict__ A, const float* __restrict__ W,
    float* __restrict__ P, int M, int N, int K, int kchunk, int zoff)
{
  __shared__ float As[32][68];
  __shared__ __align__(16) float Bs[32][64];
  int tid = threadIdx.x;
  int bm = blockIdx.y*64, bn = blockIdx.x*64;
  int kbeg = blockIdx.z*kchunk;
  int kend = min(kbeg + kchunk, K);
  float* Pz = P + (size_t)(zoff + blockIdx.z)*M*N;
  int ty = tid >> 4, tx = tid & 15;
  float acc[4][4] = {};
  for (int k0 = kbeg; k0 < kend; k0 += 32){
#pragma unroll
    for (int i=0;i<2;i++){
      int lin = tid + i*256;
      int r = lin >> 3;
      int kq = (lin & 7) * 4;
      float4 av = make_float4(0.f,0.f,0.f,0.f);
      int row = bm + r;
      if (row < M) av = *reinterpret_cast<const float4*>(A + (size_t)row*K + k0 + kq);
      As[kq+0][r]=av.x; As[kq+1][r]=av.y; As[kq+2][r]=av.z; As[kq+3][r]=av.w;
    }
#pragma unroll
    for (int i=0;i<2;i++){
      int lin = tid + i*256;
      int kr = lin >> 4;
      int c4 = (lin & 15) * 4;
      float4 wv = *reinterpret_cast<const float4*>(W + (size_t)(k0+kr)*N + bn + c4);
      *reinterpret_cast<float4*>(&Bs[kr][c4]) = wv;
    }
    __syncthreads();
#pragma unroll
    for (int kk=0;kk<32;kk++){
      float a[4], b[4];
#pragma unroll
      for (int i=0;i<4;i++) a[i] = As[kk][ty*4+i];
#pragma unroll
      for (int j=0;j<4;j++) b[j] = Bs[kk][tx*4+j];
#pragma unroll
      for (int i=0;i<4;i++)
#pragma unroll
        for (int j=0;j<4;j++) acc[i][j] += a[i]*b[j];
    }
    __syncthreads();
  }
#pragma unroll
  for (int i=0;i<4;i++){
    int row = bm + ty*4 + i;
    if (row >= M) break;
#pragma unroll
    for (int j=0;j<4;j++)
      Pz[(size_t)row*N + bn + tx*4 + j] = acc[i][j];
  }
}

// ---------------- O[t] = bias[t&nmask] + sum_z P[z][t] ----------------
__global__ __launch_bounds__(256) void reduce_add_kernel(
    const float* __restrict__ P, const float* __restrict__ bias,
    float* __restrict__ O, int total, int nz, int nmask)
{
  int t = blockIdx.x*256 + threadIdx.x;
  if (t >= total) return;
  float s = bias[t & nmask];
  for (int z = 0; z < nz; ++z) s += P[(size_t)z*total + t];
  O[t] = s;
}

// ---------------- mean pool (bf16 in, fp32 out) ----------------
__global__ __launch_bounds__(256) void pool_kernel(const unsigned short* __restrict__ h2,
                                                   float* __restrict__ g)
{
  int t = blockIdx.x*256 + threadIdx.x;
  if (t >= NB*256) return;
  int b = t >> 8, f4 = (t & 255) * 4;
  float4 s = make_float4(0.f,0.f,0.f,0.f);
#pragma unroll
  for (int i=0;i<NPG;i++){
    ushort4 v = *reinterpret_cast<const ushort4*>(h2 + (size_t)(b*NPG+i)*1024 + f4);
    s.x += bf2f(v.x); s.y += bf2f(v.y); s.z += bf2f(v.z); s.w += bf2f(v.w);
  }
  s.x *= (1.0f/NPG); s.y *= (1.0f/NPG); s.z *= (1.0f/NPG); s.w *= (1.0f/NPG);
  *reinterpret_cast<float4*>(g + (size_t)b*1024 + f4) = s;
}

extern "C" void kernel_launch(void* const* d_in, const int* in_sizes, int n_in,
                              void* d_out, int out_size, void* d_ws, size_t ws_size,
                              hipStream_t stream)
{
  const float* x    = (const float*)d_in[0];
  const int*   ei   = (const int*)d_in[1];
  const float* ea   = (const float*)d_in[2];
  const float* fpb  = (const float*)d_in[4];
  const float* Wq1  = (const float*)d_in[5];  const float* bq1 = (const float*)d_in[6];
  const float* Wk1  = (const float*)d_in[7];  const float* bk1 = (const float*)d_in[8];
  const float* Wv1  = (const float*)d_in[9];  const float* bv1 = (const float*)d_in[10];
  const float* We1  = (const float*)d_in[11];
  const float* Ws1  = (const float*)d_in[12]; const float* bs1 = (const float*)d_in[13];
  const float* Wq2  = (const float*)d_in[14]; const float* bq2 = (const float*)d_in[15];
  const float* Wk2  = (const float*)d_in[16]; const float* bk2 = (const float*)d_in[17];
  const float* Wv2  = (const float*)d_in[18]; const float* bv2 = (const float*)d_in[19];
  const float* We2  = (const float*)d_in[20];
  const float* Ws2  = (const float*)d_in[21]; const float* bs2 = (const float*)d_in[22];
  const float* Wfp  = (const float*)d_in[23]; const float* bfp = (const float*)d_in[24];
  const float* Wfin = (const float*)d_in[25]; const float* bfin= (const float*)d_in[26];
  const int* src = ei;
  const int* dst = ei + NE;
  float* out = (float*)d_out;

  // ---- workspace layout (~255 MB peak, time-disjoint aliasing) ----
  const size_t F512  = (size_t)NN*512;
  const size_t F1024 = (size_t)NN*1024;
  float* base = (float*)d_ws;
  float* C_a = base;                    // q1b/v1b; q2b/v2b (bf16); hb at +F1024 ushorts; P1/P2
  float* C_b = base + F1024;            // k2b / s2b (bf16)
  float* H   = base + 2*F1024;          // k1b / s1b (bf16); later Wt (bf16)
  unsigned short* q1b = (unsigned short*)C_a;        // [NN,512]
  unsigned short* v1b = (unsigned short*)C_a;        // [NN,512] (q1b dead)
  unsigned short* k1b = (unsigned short*)H;          // [NN,512]
  unsigned short* s1b = (unsigned short*)H;          // [NN,512] bf16 (k1b dead)
  unsigned short* hb  = (unsigned short*)C_a + F1024;   // [MPAD,512] bf16
  unsigned short* q2b = (unsigned short*)C_a;        // [NN,1024] bf16
  unsigned short* k2b = (unsigned short*)C_b;        // [NN,1024] bf16
  unsigned short* v2b = (unsigned short*)C_a;        // [NN,1024] bf16 (q2b dead)
  unsigned short* s2b = (unsigned short*)C_b;        // [NN,1024] bf16 (k2b dead)
  unsigned short* WtQ = (unsigned short*)H;          // 4 x [1024,512] bf16 (s1b dead)
  unsigned short* WtK = WtQ + (size_t)1024*512;
  unsigned short* WtV = WtK + (size_t)1024*512;
  unsigned short* WtS = WtV + (size_t)1024*512;
  float* P1 = C_a;                            // 5 x [NB*1024]
  float* P2 = C_a + 5*(size_t)NB*1024;        // 8 x [NB*256]

  float* tail = base + 2*F1024 + F512;
  float*    alphab   = tail;                                  // NE*4 (scores -> exp)
  unsigned* amax     = (unsigned*)(alphab + (size_t)NE*4);    // NN*4
  float*    den      = (float*)(amax + (size_t)NN*4);         // NN*4
  unsigned* deg      = (unsigned*)(den + (size_t)NN*4);       // NN
  unsigned* cur      = deg + NN;                              // NN
  unsigned* rowstart = cur + NN;                              // NN+1
  int*      eidx     = (int*)(rowstart + NN + 1);             // NE
  float*    g        = (float*)(eidx + NE);                   // NB*1024
  float*    fp       = g + (size_t)NB*1024;                   // NB*256

  // ================= CSR build =================
  hipMemsetAsync(deg, 0, sizeof(unsigned)*NN, stream);
  hipMemsetAsync(cur, 0, sizeof(unsigned)*NN, stream);
  count_kernel<<<(NE+255)/256, 256, 0, stream>>>(dst, deg);
  scan_kernel<<<1, 1024, 0, stream>>>(deg, rowstart);
  scatter_kernel<<<(NE+255)/256, 256, 0, stream>>>(dst, rowstart, cur, eidx);

  // ================= Layer 1 =================
  hipMemsetAsync(amax, 0, sizeof(unsigned)*(size_t)NN*4, stream);
  hipMemsetAsync(den,  0, sizeof(float)*(size_t)NN*4, stream);

  node_gemm_l1_pair<true,true><<<(NN*512+255)/256, 256, 0, stream>>>(
      x, Wq1,bq1, Wk1,bk1, q1b, k1b);
  alpha_bf16_hc512<<<NE/4, 256, 0, stream>>>(q1b, k1b, ea, We1, src, dst, alphab, amax);
  ex_kernel<<<(NE*4+255)/256, 256, 0, stream>>>(alphab, amax, dst, den);
  node_gemm_l1_pair<true,true><<<(NN*512+255)/256, 256, 0, stream>>>(
      x, Wv1,bv1, Ws1,bs1, v1b, s1b);
  gather512_kernel<<<NN, 256, 0, stream>>>(v1b, ea, We1, src, rowstart, eidx,
                                           alphab, den, s1b, hb);
  hipMemsetAsync(hb + F512, 0, (size_t)(MPAD-NN)*512*sizeof(unsigned short), stream);

  // ================= weights to bf16 (H free: s1b dead) =================
  cvt_wt_kernel<<<(1024*512+255)/256, 256, 0, stream>>>(Wq2, WtQ);
  cvt_wt_kernel<<<(1024*512+255)/256, 256, 0, stream>>>(Wk2, WtK);
  cvt_wt_kernel<<<(1024*512+255)/256, 256, 0, stream>>>(Wv2, WtV);
  cvt_wt_kernel<<<(1024*512+255)/256, 256, 0, stream>>>(Ws2, WtS);

  // ================= Layer 2 =================
  hipMemsetAsync(amax, 0, sizeof(unsigned)*(size_t)NN*4, stream);
  hipMemsetAsync(den,  0, sizeof(float)*(size_t)NN*4, stream);

  {
    dim3 grid(8, MPAD/128);
    gemm_bf16_mfma<true><<<grid, 256, 0, stream>>>(hb, WtQ, bq2, q2b, NN);   // q2 bf16
    gemm_bf16_mfma<true><<<grid, 256, 0, stream>>>(hb, WtK, bk2, k2b, NN);   // k2 bf16
  }
  alpha_bf16_hc1024<<<NE/4, 256, 0, stream>>>(q2b, k2b, ea, We2, src, dst, alphab, amax);
  ex_kernel<<<(NE*4+255)/256, 256, 0, stream>>>(alphab, amax, dst, den);
  {
    dim3 grid(8, MPAD/128);
    gemm_bf16_mfma<true><<<grid, 256, 0, stream>>>(hb, WtV, bv2, v2b, NN);   // v2 bf16 (q2b dead)
    gemm_bf16_mfma<true><<<grid, 256, 0, stream>>>(hb, WtS, bs2, s2b, NN);   // s2 bf16 (k2b dead)
  }
  gather1024_kernel<<<NN, 256, 0, stream>>>(v2b, ea, We2, src, rowstart, eidx,
                                            alphab, den, s2b);

  // ================= pooling + head (partial split-K + reduce) =================
  pool_kernel<<<(NB*256+255)/256, 256, 0, stream>>>(s2b, g);   // C_a now dead -> P1/P2

  {
    dim3 gfp(256/64, (NB+63)/64, 8);
    sgemm_partial<<<gfp, 256, 0, stream>>>(fpb, Wfp, P2, NB, 256, 2048, 256, 0);
    reduce_add_kernel<<<(NB*256+255)/256, 256, 0, stream>>>(P2, bfp, fp, NB*256, 8, 255);
  }
  {
    dim3 g1(1024/64, (NB+63)/64, 4);
    sgemm_partial<<<g1, 256, 0, stream>>>(g, Wfin, P1, NB, 1024, 1024, 256, 0);
    dim3 g2(1024/64, (NB+63)/64, 1);
    sgemm_partial<<<g2, 256, 0, stream>>>(fp, Wfin + (size_t)1024*1024, P1, NB, 1024, 256, 256, 4);
    reduce_add_kernel<<<(NB*1024+255)/256, 256, 0, stream>>>(P1, bfin, out, NB*1024, 5, 1023);
  }
}